// Round 8
// baseline (2155.614 us; speedup 1.0000x reference)
//
#include <hip/hip_runtime.h>
#include <hip/hip_cooperative_groups.h>
#include <math.h>

namespace cg = cooperative_groups;

#define NB 16
#define SL 32
#define H5 5120
#define K3 3072

typedef __attribute__((ext_vector_type(8))) short short8;
typedef __attribute__((ext_vector_type(4))) float floatx4;

__device__ __forceinline__ float sigf(float x) { return 1.0f / (1.0f + expf(-x)); }

__device__ __forceinline__ unsigned short f2bf(float x) {
  union { float f; unsigned int u; } v;
  v.f = x;
  unsigned int r = v.u + 0x7FFFu + ((v.u >> 16) & 1u);
  return (unsigned short)(r >> 16);
}

// meta layout (ints):
//  own 0, lt 512, li 1024, rt 1536, ri 2048, dep 2560, nn 3072(16),
//  dcnt 3088(32), lcnt 3120(32), dlist 3152(32*512), llist 19536(32*512)

// ---------------- batch f32 -> bf16 conversion (6 segments) ----------------
__global__ void k_conv6(const float* s0, unsigned short* d0, int n0,
                        const float* s1, unsigned short* d1, int n1,
                        const float* s2, unsigned short* d2, int n2,
                        const float* s3, unsigned short* d3, int n3,
                        const float* s4, unsigned short* d4, int n4,
                        const float* s5, unsigned short* d5, int n5)
{
  const float* s; unsigned short* d; int n;
  switch (blockIdx.y) {
    case 0: s = s0; d = d0; n = n0; break;
    case 1: s = s1; d = d1; n = n1; break;
    case 2: s = s2; d = d2; n = n2; break;
    case 3: s = s3; d = d3; n = n3; break;
    case 4: s = s4; d = d4; n = n4; break;
    default: s = s5; d = d5; n = n5; break;
  }
  const int nf4 = n >> 2;
  for (int i = blockIdx.x * blockDim.x + threadIdx.x; i < nf4; i += gridDim.x * blockDim.x) {
    const float4 v = *(const float4*)&s[i * 4];
    ushort4 o;
    o.x = f2bf(v.x); o.y = f2bf(v.y); o.z = f2bf(v.z); o.w = f2bf(v.w);
    *(ushort4*)&d[i * 4] = o;
  }
}

// ---- generic f32 GEMM (only used for E1): out[r,g] = sum_k A[r,k]*W[g,k]
__global__ __launch_bounds__(256)
void k_gemm(const float* __restrict__ A, int lda,
            const float* __restrict__ W, int ldw,
            float* __restrict__ out, int N, int K)
{
  __shared__ __align__(16) float sm[2 * 16 * 68];
  float* As = sm;
  float* Ws = sm + 16 * 68;
  const int tid = threadIdx.x;
  const int tx = tid & 15, ty = tid >> 4;
  const int g0 = blockIdx.x * 64, r0 = blockIdx.y * 64;
  float acc[4][4];
#pragma unroll
  for (int i = 0; i < 4; ++i)
#pragma unroll
    for (int j = 0; j < 4; ++j) acc[i][j] = 0.0f;
  const int ks = tid & 15, rr = tid >> 4;
  for (int kt = 0; kt < K; kt += 16) {
#pragma unroll
    for (int rep = 0; rep < 4; ++rep) {
      As[ks * 68 + rep * 16 + rr] = A[(size_t)(r0 + rep * 16 + rr) * lda + kt + ks];
      Ws[ks * 68 + rep * 16 + rr] = W[(size_t)(g0 + rep * 16 + rr) * ldw + kt + ks];
    }
    __syncthreads();
#pragma unroll
    for (int k = 0; k < 16; ++k) {
      const float4 a4 = *(const float4*)&As[k * 68 + ty * 4];
      const float4 w4 = *(const float4*)&Ws[k * 68 + tx * 4];
      const float av[4] = {a4.x, a4.y, a4.z, a4.w};
      const float wv[4] = {w4.x, w4.y, w4.z, w4.w};
#pragma unroll
      for (int i = 0; i < 4; ++i)
#pragma unroll
        for (int j = 0; j < 4; ++j) acc[i][j] += av[i] * wv[j];
    }
    __syncthreads();
  }
#pragma unroll
  for (int i = 0; i < 4; ++i) {
    const int r = r0 + ty * 4 + i;
    float4 o;
    o.x = acc[i][0]; o.y = acc[i][1]; o.z = acc[i][2]; o.w = acc[i][3];
    *(float4*)&out[(size_t)r * N + g0 + tx * 4] = o;
  }
}

// ---------------- input projection MFMA: X = embB @ WihB^T ----------------
__global__ __launch_bounds__(256)
void k_xproj(const unsigned short* __restrict__ embB,
             const unsigned short* __restrict__ WfB, const unsigned short* __restrict__ WbB,
             float* __restrict__ Xf, float* __restrict__ Xb)
{
  const unsigned short* B = blockIdx.z ? WbB : WfB;
  float* out = blockIdx.z ? Xb : Xf;
  __shared__ __align__(16) unsigned short As[128 * 40];
  __shared__ __align__(16) unsigned short Bs[128 * 40];
  const int tid = threadIdx.x;
  const int g0 = blockIdx.x * 128;
  const int r0 = blockIdx.y * 128;
  const int wave = tid >> 6, lane = tid & 63;
  const int wm = wave >> 1, wn = wave & 1;
  const int l15 = lane & 15, quad = lane >> 4;
  floatx4 acc[4][4];
#pragma unroll
  for (int mt = 0; mt < 4; ++mt)
#pragma unroll
    for (int nt = 0; nt < 4; ++nt) acc[mt][nt] = (floatx4){0.f, 0.f, 0.f, 0.f};
  for (int kt = 0; kt < 512; kt += 32) {
    __syncthreads();
#pragma unroll
    for (int p = 0; p < 2; ++p) {
      const int i = tid + p * 256;
      const int row = i >> 2, q = i & 3;
      *(uint4*)&As[row * 40 + q * 8] = *(const uint4*)&embB[(size_t)(r0 + row) * 512 + kt + q * 8];
      *(uint4*)&Bs[row * 40 + q * 8] = *(const uint4*)&B[(size_t)(g0 + row) * 512 + kt + q * 8];
    }
    __syncthreads();
    short8 af[4], bfr[4];
#pragma unroll
    for (int mt = 0; mt < 4; ++mt)
      af[mt] = *(const short8*)&As[(wm * 64 + mt * 16 + l15) * 40 + quad * 8];
#pragma unroll
    for (int nt = 0; nt < 4; ++nt)
      bfr[nt] = *(const short8*)&Bs[(wn * 64 + nt * 16 + l15) * 40 + quad * 8];
#pragma unroll
    for (int mt = 0; mt < 4; ++mt)
#pragma unroll
      for (int nt = 0; nt < 4; ++nt)
        acc[mt][nt] = __builtin_amdgcn_mfma_f32_16x16x32_bf16(af[mt], bfr[nt], acc[mt][nt], 0, 0, 0);
  }
#pragma unroll
  for (int nt = 0; nt < 4; ++nt) {
    const int col = g0 + wn * 64 + nt * 16 + l15;
#pragma unroll
    for (int mt = 0; mt < 4; ++mt)
#pragma unroll
      for (int i = 0; i < 4; ++i) {
        const int row = r0 + wm * 64 + mt * 16 + quad * 4 + i;
        out[(size_t)row * 2048 + col] = acc[mt][nt][i];
      }
  }
}

// ---------------- big compose GEMM: gB[r,g] = bc[g] + U @ WcB^T ----------------
// M=512, N=5120, K=3072. grid 320 (4 mtiles x 80 ntiles), block 512 = 8 waves
// (wave = 64 rows x 16 cols) -> 10 waves/CU occupancy.
__global__ __launch_bounds__(512)
void k_mfma_gemm(const unsigned short* __restrict__ U, const unsigned short* __restrict__ WcB,
                 const float* __restrict__ bc, float* __restrict__ gB)
{
  __shared__ __align__(16) unsigned short As[128 * 40];
  __shared__ __align__(16) unsigned short Bs[64 * 40];
  const int bid = blockIdx.x;
  const int r0 = (bid / 80) * 128;
  const int g0 = (bid % 80) * 64;
  const int tid = threadIdx.x;
  const int wave = tid >> 6, lane = tid & 63;
  const int wm = wave >> 2, wn = wave & 3;   // wm: 2x64 rows, wn: 4x16 cols
  const int l15 = lane & 15, quad = lane >> 4;
  floatx4 acc[4];
#pragma unroll
  for (int mf = 0; mf < 4; ++mf) acc[mf] = (floatx4){0.f, 0.f, 0.f, 0.f};
  for (int kt = 0; kt < K3; kt += 32) {
    __syncthreads();
    {
      const int row = tid >> 2, q = tid & 3;
      *(uint4*)&As[row * 40 + q * 8] = *(const uint4*)&U[(size_t)(r0 + row) * K3 + kt + q * 8];
      if (tid < 256)
        *(uint4*)&Bs[row * 40 + q * 8] = *(const uint4*)&WcB[(size_t)(g0 + row) * K3 + kt + q * 8];
    }
    __syncthreads();
    const short8 b = *(const short8*)&Bs[(wn * 16 + l15) * 40 + quad * 8];
#pragma unroll
    for (int mf = 0; mf < 4; ++mf) {
      const short8 a = *(const short8*)&As[(wm * 64 + mf * 16 + l15) * 40 + quad * 8];
      acc[mf] = __builtin_amdgcn_mfma_f32_16x16x32_bf16(a, b, acc[mf], 0, 0, 0);
    }
  }
  const int col = g0 + wn * 16 + l15;
  const float bias = bc[col];
#pragma unroll
  for (int mf = 0; mf < 4; ++mf)
#pragma unroll
    for (int i = 0; i < 4; ++i) {
      const int row = r0 + wm * 64 + mf * 16 + quad * 4 + i;
      gB[(size_t)row * H5 + col] = acc[mf][i] + bias;
    }
}

// ---------------- cooperative recurrent scan (all 32 steps, 1 launch) ----------------
// grid 64 (bid = dir*32 + hjt), block 256 = 4 waves (wave = gate quarter).
// Same arithmetic order as the old per-step kernel -> bit-identical results.
__global__ __launch_bounds__(256)
void k_scan(const float* __restrict__ Xf, const float* __restrict__ Xb,
            const unsigned short* __restrict__ WhfB, const unsigned short* __restrict__ WhbB,
            const float* __restrict__ bf, const float* __restrict__ bb,
            const int* __restrict__ len,
            unsigned short* __restrict__ hbB, float* __restrict__ cbuf,
            float* __restrict__ hs, float* __restrict__ cs)
{
  cg::grid_group grid = cg::this_grid();
  const int bid = blockIdx.x;
  const int dir = bid >> 5, hjt = bid & 31;
  const int tid = threadIdx.x;
  const int wave = tid >> 6, lane = tid & 63;
  const int l15 = lane & 15, quad = lane >> 4;
  const unsigned short* Wh = dir ? WhbB : WhfB;
  const float* bias = dir ? bb : bf;
  const float* X = dir ? Xb : Xf;
  __shared__ float sg[4 * 16 * 17];
  const int jg = wave * 512 + hjt * 16 + l15;
  const int b = tid >> 4, j = tid & 15;
  const int hj = hjt * 16 + j;
  const int Lb = len[b];
  const float bi = bias[hj], bfo = bias[512 + hj], bg = bias[1024 + hj], bo = bias[1536 + hj];

  for (int t = 0; t < SL; ++t) {
    const int pp = t & 1;
    const unsigned short* hp = hbB + (size_t)(dir * 2 + pp) * 8192;
    unsigned short* hn = hbB + (size_t)(dir * 2 + (pp ^ 1)) * 8192;
    const float* cp = cbuf + (size_t)(dir * 2 + pp) * 8192;
    float* cn = cbuf + (size_t)(dir * 2 + (pp ^ 1)) * 8192;
    floatx4 acc = (floatx4){0.f, 0.f, 0.f, 0.f};
    if (t > 0) {
      for (int kt = 0; kt < 512; kt += 32) {
        const short8 a = *(const short8*)&hp[(size_t)l15 * 512 + kt + quad * 8];
        const short8 bb8 = *(const short8*)&Wh[(size_t)jg * 512 + kt + quad * 8];
        acc = __builtin_amdgcn_mfma_f32_16x16x32_bf16(a, bb8, acc, 0, 0, 0);
      }
    }
#pragma unroll
    for (int i = 0; i < 4; ++i)
      sg[wave * 272 + (quad * 4 + i) * 17 + l15] = acc[i];
    __syncthreads();
    int xidx = t;
    if (dir) xidx = (t < Lb) ? (Lb - 1 - t) : t;
    const float* xr = X + (size_t)(b * SL + xidx) * 2048;
    const float gi = sg[0 * 272 + b * 17 + j] + xr[hj] + bi;
    const float gf = sg[1 * 272 + b * 17 + j] + xr[512 + hj] + bfo;
    const float gg = sg[2 * 272 + b * 17 + j] + xr[1024 + hj] + bg;
    const float go = sg[3 * 272 + b * 17 + j] + xr[1536 + hj] + bo;
    const float cprev = (t > 0) ? cp[b * 512 + hj] : 0.0f;
    const float cnew = sigf(gf) * cprev + sigf(gi) * tanhf(gg);
    const float hnew = sigf(go) * tanhf(cnew);
    cn[b * 512 + hj] = cnew;
    hn[b * 512 + hj] = f2bf(hnew);
    const int pos = dir ? xidx : t;
    const int col = dir ? (512 + hj) : hj;
    hs[(size_t)(b * SL + pos) * 1024 + col] = hnew;
    cs[(size_t)(b * SL + pos) * 1024 + col] = cnew;
    if (t < SL - 1) {
      __threadfence();
      grid.sync();
    }
  }
}

// ---------------- precompute ALL segment argmax splits ----------------
__global__ __launch_bounds__(256)
void k_score(const float* __restrict__ E1, const float* __restrict__ Wr1,
             const float* __restrict__ Wr2, const int* __restrict__ len,
             int* __restrict__ ksplit, int* __restrict__ meta)
{
  const int b = blockIdx.x;
  const int s = blockIdx.y;
  const int tid = threadIdx.x;
  if (b == 0 && s == 0 && tid < 64) meta[3088 + tid] = 0;  // zero dcnt+lcnt
  const int L = len[b];
  if (s + 2 > L) return;
  __shared__ float e[32 * 257];
  __shared__ float w1p[256];
  __shared__ float w2s[256];
  __shared__ float red[32 * 8];
  __shared__ float sc[32];
  const int nrow = 32 - s;
  for (int i = tid; i < nrow * 256; i += 256) {
    const int rr = i >> 8, q = i & 255;
    e[rr * 257 + q] = E1[(size_t)(b * SL + s + rr) * 256 + q];
  }
  w1p[tid] = Wr1[tid * 513 + 512];
  w2s[tid] = Wr2[tid];
  __syncthreads();
  const int t_ = tid & 31, jg = tid >> 5;
  const int lmax = L - s;
  for (int l = 2; l <= lmax; ++l) {
    float part = 0.0f;
    if (t_ < l) {
      const float pos = 2.0f * (float)t_ / (float)l - 1.0f;
      const float* er = e + t_ * 257;
      for (int q = jg * 32; q < jg * 32 + 32; ++q) {
        const float v = er[q] + pos * w1p[q];
        part += fmaxf(v, 0.0f) * w2s[q];
      }
    }
    red[t_ * 8 + jg] = part;
    __syncthreads();
    if (jg == 0 && t_ < l) {
      float su = 0.0f;
      for (int q = 0; q < 8; ++q) su += red[t_ * 8 + q];
      sc[t_] = su;
    }
    __syncthreads();
    if (tid == 0) {
      int k = 0;
      float best = sc[0];
      for (int q = 1; q < l; ++q)
        if (sc[q] > best) { best = sc[q]; k = q; }
      ksplit[(b * 32 + s) * 33 + l] = k;
    }
    __syncthreads();
  }
}

// ---------------- DFS walk using precomputed splits ----------------
__global__ __launch_bounds__(64)
void k_walk(const int* __restrict__ ksplit, const int* __restrict__ len,
            int* __restrict__ meta)
{
  const int b = blockIdx.x;
  const int tid = threadIdx.x;
  __shared__ int ks[32 * 33];
  __shared__ int stk[96];
  for (int i = tid; i < 32 * 33; i += 64) ks[i] = ksplit[b * 1056 + i];
  __syncthreads();
  if (tid != 0) return;
  int* own = meta;
  int* lt = meta + 512;
  int* li = meta + 1024;
  int* rt = meta + 1536;
  int* ri = meta + 2048;
  int* dep = meta + 2560;
  int* nn = meta + 3072;
  int* dcnt = meta + 3088;
  int* lcnt = meta + 3120;
  int* dlist = meta + 3152;
  int* llist = meta + 19536;
  int sp = 0, nn_ = 1;
  stk[0] = 0; stk[1] = len[b]; stk[2] = 0;
  sp = 1;
  while (sp > 0) {
    sp--;
    const int s = stk[sp * 3], eN = stk[sp * 3 + 1], nid = stk[sp * 3 + 2];
    const int l = eN - s;
    const int k = ks[s * 33 + l];
    const int m = b * 32 + nid;
    own[m] = s + k;
    if (k == 0) { lt[m] = 0; li[m] = 0; }
    else if (k == 1) { lt[m] = 1; li[m] = s; }
    else {
      const int id = nn_++;
      lt[m] = 2; li[m] = id;
      stk[sp * 3] = s; stk[sp * 3 + 1] = s + k; stk[sp * 3 + 2] = id; sp++;
    }
    const int rl = l - k - 1;
    if (rl == 0) { rt[m] = 0; ri[m] = 0; }
    else if (rl == 1) { rt[m] = 1; ri[m] = s + k + 1; }
    else {
      const int id = nn_++;
      rt[m] = 2; ri[m] = id;
      stk[sp * 3] = s + k + 1; stk[sp * 3 + 1] = eN; stk[sp * 3 + 2] = id; sp++;
    }
  }
  nn[b] = nn_;
  for (int i = nn_ - 1; i >= 0; --i) {
    const int m = b * 32 + i;
    int d = 1;
    if (lt[m] == 2) d = max(d, dep[b * 32 + li[m]] + 1);
    if (rt[m] == 2) d = max(d, dep[b * 32 + ri[m]] + 1);
    dep[m] = d;
  }
  for (int i = 0; i < nn_; ++i) {
    const int m = b * 32 + i;
    const int r = dep[m];
    const int idx = atomicAdd(&dcnt[r], 1);
    dlist[r * 512 + idx] = m;
    if (lt[m] == 2 || rt[m] == 2) {
      const int lx = atomicAdd(&lcnt[r], 1);
      llist[r * 512 + lx] = m;
    }
  }
}

// ---------------- build U (bf16) = [hl_leaf|0 , hr_leaf|0 , hx] per node ----------------
__global__ __launch_bounds__(256)
void k_ubuild(const float* __restrict__ hs, const int* __restrict__ meta,
              unsigned short* __restrict__ U)
{
  const int id = blockIdx.x, b = blockIdx.y;
  const int tid = threadIdx.x;
  const int* own = meta;
  const int* lt = meta + 512;
  const int* li = meta + 1024;
  const int* rt = meta + 1536;
  const int* ri = meta + 2048;
  const int* nn = meta + 3072;
  const int m = b * 32 + id;
  unsigned short* u = U + (size_t)m * K3;
  if (id >= nn[b]) {
    for (int i = tid; i < K3; i += 256) u[i] = 0;
    return;
  }
  const float* hl = (lt[m] == 1) ? hs + (size_t)(b * 32 + li[m]) * 1024 : nullptr;
  const float* hr = (rt[m] == 1) ? hs + (size_t)(b * 32 + ri[m]) * 1024 : nullptr;
  const float* hx = hs + (size_t)(b * 32 + own[m]) * 1024;
  for (int i = tid; i < 1024; i += 256) {
    u[i] = hl ? f2bf(hl[i]) : 0;
    u[1024 + i] = hr ? f2bf(hr[i]) : 0;
    u[2048 + i] = f2bf(hx[i]);
  }
}

// ---------------- cooperative tail: ALL compose rounds in one launch ----------------
// grid 320 (block owns 16 Wc rows, staged to LDS ONCE), block 256 = 4 waves.
// Per round: link phase (waves process 16-node chunks, full K=2048, no
// cross-wave reduce) -> fence+sync -> gate phase (work spread over all
// blocks) -> fence+sync. Empty rounds break uniformly (depths contiguous).
__global__ __launch_bounds__(256)
void k_tail(const unsigned short* __restrict__ WcB, const int* __restrict__ meta,
            const float* __restrict__ gB, const float* __restrict__ cs,
            float* __restrict__ nodec, unsigned short* __restrict__ nodehb,
            float* __restrict__ linkacc, float* __restrict__ out)
{
  cg::grid_group grid = cg::this_grid();
  const int* lt = meta + 512;
  const int* li = meta + 1024;
  const int* rt = meta + 1536;
  const int* ri = meta + 2048;
  const int* dcnt = meta + 3088;
  const int* dlist = meta + 3152;
  const int* llist = meta + 19536;
  const int bid = blockIdx.x;
  const int tid = threadIdx.x;
  const int wave = tid >> 6, lane = tid & 63;
  const int l15 = lane & 15, quad = lane >> 4;
  const int g0 = bid * 16;
  __shared__ __align__(16) unsigned short Bs[16 * 2048];  // 64 KB, lives whole kernel
  const short8 z8 = {0, 0, 0, 0, 0, 0, 0, 0};

  // stage this block's 16 Wc rows (k-major: Bs[kq*128 + row*8]) once
  {
    const int row = tid & 15;
    const int kqb = tid >> 4;
#pragma unroll
    for (int it = 0; it < 16; ++it) {
      const int kq = kqb + it * 16;
      *(uint4*)&Bs[kq * 128 + row * 8] =
          *(const uint4*)&WcB[(size_t)(g0 + row) * K3 + kq * 8];
    }
  }
  __syncthreads();

  // gate phase helper (uselink: add linkacc)
  auto gate_phase = [&](int r, bool uselink) {
    const int cnt = dcnt[r];
    for (int w = bid * 256 + tid; w < cnt * 256; w += 320 * 256) {
      const int m = w >> 8;
      const int hj = (w & 255) * 4;
      const int node = dlist[r * 512 + m];
      const int base = node & ~31;
      const int ltv = lt[node], rtv = rt[node];
      const float* clp = (ltv == 2) ? &nodec[(size_t)(base + li[node]) * 1024]
                       : (ltv == 1) ? &cs[(size_t)(base + li[node]) * 1024] : nullptr;
      const float* crp = (rtv == 2) ? &nodec[(size_t)(base + ri[node]) * 1024]
                       : (rtv == 1) ? &cs[(size_t)(base + ri[node]) * 1024] : nullptr;
      const float* g = &gB[(size_t)node * H5 + hj];
      const float* la = &linkacc[(size_t)node * H5 + hj];
      const float4 gi4  = *(const float4*)&g[0];
      const float4 gfl4 = *(const float4*)&g[1024];
      const float4 gfr4 = *(const float4*)&g[2048];
      const float4 gu4  = *(const float4*)&g[3072];
      const float4 go4  = *(const float4*)&g[4096];
      float4 li4 = make_float4(0.f, 0.f, 0.f, 0.f), lf4 = li4, lr4 = li4,
             lu4 = li4, lo4 = li4;
      if (uselink) {
        li4 = *(const float4*)&la[0];
        lf4 = *(const float4*)&la[1024];
        lr4 = *(const float4*)&la[2048];
        lu4 = *(const float4*)&la[3072];
        lo4 = *(const float4*)&la[4096];
      }
      const float gis[4] = {gi4.x + li4.x, gi4.y + li4.y, gi4.z + li4.z, gi4.w + li4.w};
      const float gfs[4] = {gfl4.x + lf4.x, gfl4.y + lf4.y, gfl4.z + lf4.z, gfl4.w + lf4.w};
      const float grs[4] = {gfr4.x + lr4.x, gfr4.y + lr4.y, gfr4.z + lr4.z, gfr4.w + lr4.w};
      const float gus[4] = {gu4.x + lu4.x, gu4.y + lu4.y, gu4.z + lu4.z, gu4.w + lu4.w};
      const float gos[4] = {go4.x + lo4.x, go4.y + lo4.y, go4.z + lo4.z, go4.w + lo4.w};
      const bool isroot = (node & 31) == 0;
      const int sb = node >> 5;
#pragma unroll
      for (int q = 0; q < 4; ++q) {
        const float cl = clp ? clp[hj + q] : 0.0f;
        const float cr = crp ? crp[hj + q] : 0.0f;
        const float c = sigf(gfs[q]) * cl + sigf(grs[q]) * cr + sigf(gis[q]) * tanhf(gus[q]);
        const float h = sigf(gos[q]) * tanhf(c);
        nodec[(size_t)node * 1024 + hj + q] = c;
        nodehb[(size_t)node * 1024 + hj + q] = f2bf(h);
        if (isroot) {
          out[sb * 1024 + hj + q] = h;
          out[16384 + sb * 1024 + hj + q] = c;
        }
      }
    }
  };

  // round 1: gate-only (all children are leaves)
  gate_phase(1, false);
  __threadfence();
  grid.sync();

  for (int r = 2; r <= 31; ++r) {
    const int cnt = dcnt[r];   // == lcnt[r] membership for r>=2
    if (cnt == 0) break;
    // ---- link phase: wave w handles chunks w, w+4, ... (full K per wave) ----
    for (int ch = wave; ch * 16 < cnt; ch += 4) {
      const int m0 = ch * 16;
      const int m = m0 + l15;
      int ofs_l = -1, ofs_r = -1;
      if (m < cnt) {
        const int node = llist[r * 512 + m];
        const int base = node & ~31;
        if (lt[node] == 2) ofs_l = (base + li[node]) * 1024;
        if (rt[node] == 2) ofs_r = (base + ri[node]) * 1024;
      }
      floatx4 acc = (floatx4){0.f, 0.f, 0.f, 0.f};
      const int kq = quad * 8;
#pragma unroll 4
      for (int s = 0; s < 32; ++s) {
        const int k = s * 32 + kq;
        const short8 b8 = *(const short8*)&Bs[(k >> 3) * 128 + l15 * 8];
        const short8 a8 = (ofs_l >= 0) ? *(const short8*)&nodehb[(size_t)ofs_l + k] : z8;
        acc = __builtin_amdgcn_mfma_f32_16x16x32_bf16(a8, b8, acc, 0, 0, 0);
      }
#pragma unroll 4
      for (int s = 32; s < 64; ++s) {
        const int k = s * 32 + kq;
        const short8 b8 = *(const short8*)&Bs[(k >> 3) * 128 + l15 * 8];
        const short8 a8 = (ofs_r >= 0) ? *(const short8*)&nodehb[(size_t)ofs_r + k - 1024] : z8;
        acc = __builtin_amdgcn_mfma_f32_16x16x32_bf16(a8, b8, acc, 0, 0, 0);
      }
      // D: row(quad*4+i) = node idx in chunk, col(l15) = this block's Wc row
#pragma unroll
      for (int i = 0; i < 4; ++i) {
        const int mm = m0 + quad * 4 + i;
        if (mm < cnt) {
          const int nodei = llist[r * 512 + mm];
          linkacc[(size_t)nodei * H5 + g0 + l15] = acc[i];
        }
      }
    }
    __threadfence();
    grid.sync();
    // ---- gate phase ----
    gate_phase(r, true);
    __threadfence();
    grid.sync();
  }
}

extern "C" void kernel_launch(void* const* d_in, const int* in_sizes, int n_in,
                              void* d_out, int out_size, void* d_ws, size_t ws_size,
                              hipStream_t stream) {
  const float* emb = (const float*)d_in[0];
  const int* len = (const int*)d_in[1];
  const float* Wihf = (const float*)d_in[2];
  const float* Whhf = (const float*)d_in[3];
  const float* bf = (const float*)d_in[4];
  const float* Wihb = (const float*)d_in[5];
  const float* Whhb = (const float*)d_in[6];
  const float* bb = (const float*)d_in[7];
  const float* Wr1 = (const float*)d_in[8];
  const float* Wr2 = (const float*)d_in[9];
  const float* Wc = (const float*)d_in[10];
  const float* bc = (const float*)d_in[11];
  float* out = (float*)d_out;

  float* ws = (float*)d_ws;
  float* Xf = ws;                                         // 1048576 f
  float* Xb = Xf + 1048576;                               // 1048576 f
  float* hs = Xb + 1048576;                               // 524288 f
  float* cs = hs + 524288;                                // 524288 f
  float* E1 = cs + 524288;                                // 131072 f
  unsigned short* U = (unsigned short*)(E1 + 131072);     // 786432 f
  float* gB = (float*)U + 786432;                         // 2621440 f
  float* nodec = gB + 2621440;                            // 524288 f
  unsigned short* nodehb = (unsigned short*)(nodec + 524288);     // 262144 f
  float* cbuf = (float*)nodehb + 262144;                  // 32768 f
  unsigned short* hbB = (unsigned short*)(cbuf + 32768);  // 16384 f
  unsigned short* WcB = (unsigned short*)((float*)hbB + 16384);   // 7864320 f
  unsigned short* WihfB = WcB + 15728640;                 // 1048576 sh
  unsigned short* WihbB = WihfB + 1048576;
  unsigned short* WhhfB = WihbB + 1048576;
  unsigned short* WhhbB = WhhfB + 1048576;
  unsigned short* embB = WhhbB + 1048576;                 // 262144 sh
  int* meta = (int*)(embB + 262144);                      // ~36K ints
  int* ksplit = meta + 36096;                             // 16*1056 ints
  // linkacc (512 x 5120 f = exactly Xf+Xb+hs) aliases buffers dead after ubuild
  float* linkacc = ws;

  // bf16 conversions
  k_conv6<<<dim3(1920, 6), 256, 0, stream>>>(
      Wc, WcB, 15728640, Wihf, WihfB, 1048576, Wihb, WihbB, 1048576,
      Whhf, WhhfB, 1048576, Whhb, WhhbB, 1048576, emb, embB, 262144);
  // rank projection (f32)
  k_gemm<<<dim3(4, 8), 256, 0, stream>>>(emb, 512, Wr1, 513, E1, 256, 512);
  // input projections
  k_xproj<<<dim3(16, 4, 2), 256, 0, stream>>>(embB, WihfB, WihbB, Xf, Xb);
  // recurrent scan: ONE cooperative launch, 32 internal grid.syncs
  {
    void* args[] = {(void*)&Xf, (void*)&Xb, (void*)&WhhfB, (void*)&WhhbB,
                    (void*)&bf, (void*)&bb, (void*)&len, (void*)&hbB,
                    (void*)&cbuf, (void*)&hs, (void*)&cs};
    hipLaunchCooperativeKernel((const void*)k_scan, dim3(64), dim3(256),
                               args, 0, stream);
  }
  // split table (+dcnt/lcnt zeroing) + DFS walk
  k_score<<<dim3(16, 31), 256, 0, stream>>>(E1, Wr1, Wr2, len, ksplit, meta);
  k_walk<<<16, 64, 0, stream>>>(ksplit, len, meta);
  // precomputable part of every compose
  k_ubuild<<<dim3(32, 16), 256, 0, stream>>>(hs, meta, U);
  k_mfma_gemm<<<320, 512, 0, stream>>>(U, WcB, bc, gB);
  // ALL compose rounds + gating + output: ONE cooperative launch
  {
    void* args[] = {(void*)&WcB, (void*)&meta, (void*)&gB, (void*)&cs,
                    (void*)&nodec, (void*)&nodehb, (void*)&linkacc, (void*)&out};
    hipLaunchCooperativeKernel((const void*)k_tail, dim3(320), dim3(256),
                               args, 0, stream);
  }
}

// Round 9
// 1807.422 us; speedup vs baseline: 1.1926x; 1.1926x over previous
//
#include <hip/hip_runtime.h>
#include <math.h>

#define NB 16
#define SL 32
#define H5 5120
#define K3 3072

typedef __attribute__((ext_vector_type(8))) short short8;
typedef __attribute__((ext_vector_type(4))) float floatx4;

__device__ __forceinline__ float sigf(float x) { return 1.0f / (1.0f + expf(-x)); }

__device__ __forceinline__ unsigned short f2bf(float x) {
  union { float f; unsigned int u; } v;
  v.f = x;
  unsigned int r = v.u + 0x7FFFu + ((v.u >> 16) & 1u);
  return (unsigned short)(r >> 16);
}

// custom grid barrier: one-shot counter per instance (zeroed by k_conv6 each call).
// release-increment by thread 0, acquire-spin with short s_sleep (no runtime backoff).
__device__ __forceinline__ void gbar(int* cnt, int target) {
  __threadfence();
  __syncthreads();
  if (threadIdx.x == 0) {
    __hip_atomic_fetch_add(cnt, 1, __ATOMIC_RELEASE, __HIP_MEMORY_SCOPE_AGENT);
    while (__hip_atomic_load(cnt, __ATOMIC_ACQUIRE, __HIP_MEMORY_SCOPE_AGENT) < target)
      __builtin_amdgcn_s_sleep(1);
  }
  __syncthreads();
}

// meta layout (ints):
//  own 0, lt 512, li 1024, rt 1536, ri 2048, dep 2560, nn 3072(16),
//  dcnt 3088(32), lcnt 3120(32), dlist 3152(32*512), llist 19536(32*512)
// ksplit: meta+36096 (16*1056); bar: meta+52992 (128)

// ---------------- batch f32 -> bf16 conversion (6 segments) + barrier zeroing ----------------
__global__ void k_conv6(const float* s0, unsigned short* d0, int n0,
                        const float* s1, unsigned short* d1, int n1,
                        const float* s2, unsigned short* d2, int n2,
                        const float* s3, unsigned short* d3, int n3,
                        const float* s4, unsigned short* d4, int n4,
                        const float* s5, unsigned short* d5, int n5,
                        int* bar)
{
  if (blockIdx.y == 0 && blockIdx.x == 0 && threadIdx.x < 128) bar[threadIdx.x] = 0;
  const float* s; unsigned short* d; int n;
  switch (blockIdx.y) {
    case 0: s = s0; d = d0; n = n0; break;
    case 1: s = s1; d = d1; n = n1; break;
    case 2: s = s2; d = d2; n = n2; break;
    case 3: s = s3; d = d3; n = n3; break;
    case 4: s = s4; d = d4; n = n4; break;
    default: s = s5; d = d5; n = n5; break;
  }
  const int nf4 = n >> 2;
  for (int i = blockIdx.x * blockDim.x + threadIdx.x; i < nf4; i += gridDim.x * blockDim.x) {
    const float4 v = *(const float4*)&s[i * 4];
    ushort4 o;
    o.x = f2bf(v.x); o.y = f2bf(v.y); o.z = f2bf(v.z); o.w = f2bf(v.w);
    *(ushort4*)&d[i * 4] = o;
  }
}

// ---- generic f32 GEMM (only used for E1): out[r,g] = sum_k A[r,k]*W[g,k]
__global__ __launch_bounds__(256)
void k_gemm(const float* __restrict__ A, int lda,
            const float* __restrict__ W, int ldw,
            float* __restrict__ out, int N, int K)
{
  __shared__ __align__(16) float sm[2 * 16 * 68];
  float* As = sm;
  float* Ws = sm + 16 * 68;
  const int tid = threadIdx.x;
  const int tx = tid & 15, ty = tid >> 4;
  const int g0 = blockIdx.x * 64, r0 = blockIdx.y * 64;
  float acc[4][4];
#pragma unroll
  for (int i = 0; i < 4; ++i)
#pragma unroll
    for (int j = 0; j < 4; ++j) acc[i][j] = 0.0f;
  const int ks = tid & 15, rr = tid >> 4;
  for (int kt = 0; kt < K; kt += 16) {
#pragma unroll
    for (int rep = 0; rep < 4; ++rep) {
      As[ks * 68 + rep * 16 + rr] = A[(size_t)(r0 + rep * 16 + rr) * lda + kt + ks];
      Ws[ks * 68 + rep * 16 + rr] = W[(size_t)(g0 + rep * 16 + rr) * ldw + kt + ks];
    }
    __syncthreads();
#pragma unroll
    for (int k = 0; k < 16; ++k) {
      const float4 a4 = *(const float4*)&As[k * 68 + ty * 4];
      const float4 w4 = *(const float4*)&Ws[k * 68 + tx * 4];
      const float av[4] = {a4.x, a4.y, a4.z, a4.w};
      const float wv[4] = {w4.x, w4.y, w4.z, w4.w};
#pragma unroll
      for (int i = 0; i < 4; ++i)
#pragma unroll
        for (int j = 0; j < 4; ++j) acc[i][j] += av[i] * wv[j];
    }
    __syncthreads();
  }
#pragma unroll
  for (int i = 0; i < 4; ++i) {
    const int r = r0 + ty * 4 + i;
    float4 o;
    o.x = acc[i][0]; o.y = acc[i][1]; o.z = acc[i][2]; o.w = acc[i][3];
    *(float4*)&out[(size_t)r * N + g0 + tx * 4] = o;
  }
}

// ---------------- input projection MFMA: X = embB @ WihB^T ----------------
__global__ __launch_bounds__(256)
void k_xproj(const unsigned short* __restrict__ embB,
             const unsigned short* __restrict__ WfB, const unsigned short* __restrict__ WbB,
             float* __restrict__ Xf, float* __restrict__ Xb)
{
  const unsigned short* B = blockIdx.z ? WbB : WfB;
  float* out = blockIdx.z ? Xb : Xf;
  __shared__ __align__(16) unsigned short As[128 * 40];
  __shared__ __align__(16) unsigned short Bs[128 * 40];
  const int tid = threadIdx.x;
  const int g0 = blockIdx.x * 128;
  const int r0 = blockIdx.y * 128;
  const int wave = tid >> 6, lane = tid & 63;
  const int wm = wave >> 1, wn = wave & 1;
  const int l15 = lane & 15, quad = lane >> 4;
  floatx4 acc[4][4];
#pragma unroll
  for (int mt = 0; mt < 4; ++mt)
#pragma unroll
    for (int nt = 0; nt < 4; ++nt) acc[mt][nt] = (floatx4){0.f, 0.f, 0.f, 0.f};
  for (int kt = 0; kt < 512; kt += 32) {
    __syncthreads();
#pragma unroll
    for (int p = 0; p < 2; ++p) {
      const int i = tid + p * 256;
      const int row = i >> 2, q = i & 3;
      *(uint4*)&As[row * 40 + q * 8] = *(const uint4*)&embB[(size_t)(r0 + row) * 512 + kt + q * 8];
      *(uint4*)&Bs[row * 40 + q * 8] = *(const uint4*)&B[(size_t)(g0 + row) * 512 + kt + q * 8];
    }
    __syncthreads();
    short8 af[4], bfr[4];
#pragma unroll
    for (int mt = 0; mt < 4; ++mt)
      af[mt] = *(const short8*)&As[(wm * 64 + mt * 16 + l15) * 40 + quad * 8];
#pragma unroll
    for (int nt = 0; nt < 4; ++nt)
      bfr[nt] = *(const short8*)&Bs[(wn * 64 + nt * 16 + l15) * 40 + quad * 8];
#pragma unroll
    for (int mt = 0; mt < 4; ++mt)
#pragma unroll
      for (int nt = 0; nt < 4; ++nt)
        acc[mt][nt] = __builtin_amdgcn_mfma_f32_16x16x32_bf16(af[mt], bfr[nt], acc[mt][nt], 0, 0, 0);
  }
#pragma unroll
  for (int nt = 0; nt < 4; ++nt) {
    const int col = g0 + wn * 64 + nt * 16 + l15;
#pragma unroll
    for (int mt = 0; mt < 4; ++mt)
#pragma unroll
      for (int i = 0; i < 4; ++i) {
        const int row = r0 + wm * 64 + mt * 16 + quad * 4 + i;
        out[(size_t)row * 2048 + col] = acc[mt][nt][i];
      }
  }
}

// ---------------- big compose GEMM: gB[r,g] = bc[g] + U @ WcB^T ----------------
// grid 320 (4 mtiles x 80 ntiles), block 512 = 8 waves -> 10 waves/CU.
__global__ __launch_bounds__(512)
void k_mfma_gemm(const unsigned short* __restrict__ U, const unsigned short* __restrict__ WcB,
                 const float* __restrict__ bc, float* __restrict__ gB)
{
  __shared__ __align__(16) unsigned short As[128 * 40];
  __shared__ __align__(16) unsigned short Bs[64 * 40];
  const int bid = blockIdx.x;
  const int r0 = (bid / 80) * 128;
  const int g0 = (bid % 80) * 64;
  const int tid = threadIdx.x;
  const int wave = tid >> 6, lane = tid & 63;
  const int wm = wave >> 2, wn = wave & 3;
  const int l15 = lane & 15, quad = lane >> 4;
  floatx4 acc[4];
#pragma unroll
  for (int mf = 0; mf < 4; ++mf) acc[mf] = (floatx4){0.f, 0.f, 0.f, 0.f};
  for (int kt = 0; kt < K3; kt += 32) {
    __syncthreads();
    {
      const int row = tid >> 2, q = tid & 3;
      *(uint4*)&As[row * 40 + q * 8] = *(const uint4*)&U[(size_t)(r0 + row) * K3 + kt + q * 8];
      if (tid < 256)
        *(uint4*)&Bs[row * 40 + q * 8] = *(const uint4*)&WcB[(size_t)(g0 + row) * K3 + kt + q * 8];
    }
    __syncthreads();
    const short8 b = *(const short8*)&Bs[(wn * 16 + l15) * 40 + quad * 8];
#pragma unroll
    for (int mf = 0; mf < 4; ++mf) {
      const short8 a = *(const short8*)&As[(wm * 64 + mf * 16 + l15) * 40 + quad * 8];
      acc[mf] = __builtin_amdgcn_mfma_f32_16x16x32_bf16(a, b, acc[mf], 0, 0, 0);
    }
  }
  const int col = g0 + wn * 16 + l15;
  const float bias = bc[col];
#pragma unroll
  for (int mf = 0; mf < 4; ++mf)
#pragma unroll
    for (int i = 0; i < 4; ++i) {
      const int row = r0 + wm * 64 + mf * 16 + quad * 4 + i;
      gB[(size_t)row * H5 + col] = acc[mf][i] + bias;
    }
}

// ---------------- recurrent scan: 1 launch, custom barriers ----------------
// grid 64 (bid = dir*32 + hjt), block 256 = 4 waves (wave = gate quarter).
__global__ __launch_bounds__(256)
void k_scan(const float* __restrict__ Xf, const float* __restrict__ Xb,
            const unsigned short* __restrict__ WhfB, const unsigned short* __restrict__ WhbB,
            const float* __restrict__ bf, const float* __restrict__ bb,
            const int* __restrict__ len,
            unsigned short* __restrict__ hbB, float* __restrict__ cbuf,
            float* __restrict__ hs, float* __restrict__ cs, int* __restrict__ bar)
{
  const int bid = blockIdx.x;
  const int dir = bid >> 5, hjt = bid & 31;
  const int tid = threadIdx.x;
  const int wave = tid >> 6, lane = tid & 63;
  const int l15 = lane & 15, quad = lane >> 4;
  const unsigned short* Wh = dir ? WhbB : WhfB;
  const float* bias = dir ? bb : bf;
  const float* X = dir ? Xb : Xf;
  __shared__ float sg[4 * 16 * 17];
  const int jg = wave * 512 + hjt * 16 + l15;
  const int b = tid >> 4, j = tid & 15;
  const int hj = hjt * 16 + j;
  const int Lb = len[b];
  const float bi = bias[hj], bfo = bias[512 + hj], bg = bias[1024 + hj], bo = bias[1536 + hj];

  for (int t = 0; t < SL; ++t) {
    const int pp = t & 1;
    const unsigned short* hp = hbB + (size_t)(dir * 2 + pp) * 8192;
    unsigned short* hn = hbB + (size_t)(dir * 2 + (pp ^ 1)) * 8192;
    const float* cp = cbuf + (size_t)(dir * 2 + pp) * 8192;
    float* cn = cbuf + (size_t)(dir * 2 + (pp ^ 1)) * 8192;
    floatx4 acc = (floatx4){0.f, 0.f, 0.f, 0.f};
    if (t > 0) {
      for (int kt = 0; kt < 512; kt += 32) {
        const short8 a = *(const short8*)&hp[(size_t)l15 * 512 + kt + quad * 8];
        const short8 bb8 = *(const short8*)&Wh[(size_t)jg * 512 + kt + quad * 8];
        acc = __builtin_amdgcn_mfma_f32_16x16x32_bf16(a, bb8, acc, 0, 0, 0);
      }
    }
#pragma unroll
    for (int i = 0; i < 4; ++i)
      sg[wave * 272 + (quad * 4 + i) * 17 + l15] = acc[i];
    __syncthreads();
    int xidx = t;
    if (dir) xidx = (t < Lb) ? (Lb - 1 - t) : t;
    const float* xr = X + (size_t)(b * SL + xidx) * 2048;
    const float gi = sg[0 * 272 + b * 17 + j] + xr[hj] + bi;
    const float gf = sg[1 * 272 + b * 17 + j] + xr[512 + hj] + bfo;
    const float gg = sg[2 * 272 + b * 17 + j] + xr[1024 + hj] + bg;
    const float go = sg[3 * 272 + b * 17 + j] + xr[1536 + hj] + bo;
    const float cprev = (t > 0) ? cp[b * 512 + hj] : 0.0f;
    const float cnew = sigf(gf) * cprev + sigf(gi) * tanhf(gg);
    const float hnew = sigf(go) * tanhf(cnew);
    cn[b * 512 + hj] = cnew;
    hn[b * 512 + hj] = f2bf(hnew);
    const int pos = dir ? xidx : t;
    const int col = dir ? (512 + hj) : hj;
    hs[(size_t)(b * SL + pos) * 1024 + col] = hnew;
    cs[(size_t)(b * SL + pos) * 1024 + col] = cnew;
    if (t < SL - 1) gbar(&bar[t], 64);
  }
}

// ---------------- precompute ALL segment argmax splits ----------------
__global__ __launch_bounds__(256)
void k_score(const float* __restrict__ E1, const float* __restrict__ Wr1,
             const float* __restrict__ Wr2, const int* __restrict__ len,
             int* __restrict__ ksplit, int* __restrict__ meta)
{
  const int b = blockIdx.x;
  const int s = blockIdx.y;
  const int tid = threadIdx.x;
  if (b == 0 && s == 0 && tid < 64) meta[3088 + tid] = 0;  // zero dcnt+lcnt
  const int L = len[b];
  if (s + 2 > L) return;
  __shared__ float e[32 * 257];
  __shared__ float w1p[256];
  __shared__ float w2s[256];
  __shared__ float red[32 * 8];
  __shared__ float sc[32];
  const int nrow = 32 - s;
  for (int i = tid; i < nrow * 256; i += 256) {
    const int rr = i >> 8, q = i & 255;
    e[rr * 257 + q] = E1[(size_t)(b * SL + s + rr) * 256 + q];
  }
  w1p[tid] = Wr1[tid * 513 + 512];
  w2s[tid] = Wr2[tid];
  __syncthreads();
  const int t_ = tid & 31, jg = tid >> 5;
  const int lmax = L - s;
  for (int l = 2; l <= lmax; ++l) {
    float part = 0.0f;
    if (t_ < l) {
      const float pos = 2.0f * (float)t_ / (float)l - 1.0f;
      const float* er = e + t_ * 257;
      for (int q = jg * 32; q < jg * 32 + 32; ++q) {
        const float v = er[q] + pos * w1p[q];
        part += fmaxf(v, 0.0f) * w2s[q];
      }
    }
    red[t_ * 8 + jg] = part;
    __syncthreads();
    if (jg == 0 && t_ < l) {
      float su = 0.0f;
      for (int q = 0; q < 8; ++q) su += red[t_ * 8 + q];
      sc[t_] = su;
    }
    __syncthreads();
    if (tid == 0) {
      int k = 0;
      float best = sc[0];
      for (int q = 1; q < l; ++q)
        if (sc[q] > best) { best = sc[q]; k = q; }
      ksplit[(b * 32 + s) * 33 + l] = k;
    }
    __syncthreads();
  }
}

// ---------------- DFS walk using precomputed splits ----------------
__global__ __launch_bounds__(64)
void k_walk(const int* __restrict__ ksplit, const int* __restrict__ len,
            int* __restrict__ meta)
{
  const int b = blockIdx.x;
  const int tid = threadIdx.x;
  __shared__ int ks[32 * 33];
  __shared__ int stk[96];
  for (int i = tid; i < 32 * 33; i += 64) ks[i] = ksplit[b * 1056 + i];
  __syncthreads();
  if (tid != 0) return;
  int* own = meta;
  int* lt = meta + 512;
  int* li = meta + 1024;
  int* rt = meta + 1536;
  int* ri = meta + 2048;
  int* dep = meta + 2560;
  int* nn = meta + 3072;
  int* dcnt = meta + 3088;
  int* lcnt = meta + 3120;
  int* dlist = meta + 3152;
  int* llist = meta + 19536;
  int sp = 0, nn_ = 1;
  stk[0] = 0; stk[1] = len[b]; stk[2] = 0;
  sp = 1;
  while (sp > 0) {
    sp--;
    const int s = stk[sp * 3], eN = stk[sp * 3 + 1], nid = stk[sp * 3 + 2];
    const int l = eN - s;
    const int k = ks[s * 33 + l];
    const int m = b * 32 + nid;
    own[m] = s + k;
    if (k == 0) { lt[m] = 0; li[m] = 0; }
    else if (k == 1) { lt[m] = 1; li[m] = s; }
    else {
      const int id = nn_++;
      lt[m] = 2; li[m] = id;
      stk[sp * 3] = s; stk[sp * 3 + 1] = s + k; stk[sp * 3 + 2] = id; sp++;
    }
    const int rl = l - k - 1;
    if (rl == 0) { rt[m] = 0; ri[m] = 0; }
    else if (rl == 1) { rt[m] = 1; ri[m] = s + k + 1; }
    else {
      const int id = nn_++;
      rt[m] = 2; ri[m] = id;
      stk[sp * 3] = s + k + 1; stk[sp * 3 + 1] = eN; stk[sp * 3 + 2] = id; sp++;
    }
  }
  nn[b] = nn_;
  for (int i = nn_ - 1; i >= 0; --i) {
    const int m = b * 32 + i;
    int d = 1;
    if (lt[m] == 2) d = max(d, dep[b * 32 + li[m]] + 1);
    if (rt[m] == 2) d = max(d, dep[b * 32 + ri[m]] + 1);
    dep[m] = d;
  }
  for (int i = 0; i < nn_; ++i) {
    const int m = b * 32 + i;
    const int r = dep[m];
    const int idx = atomicAdd(&dcnt[r], 1);
    dlist[r * 512 + idx] = m;
    if (lt[m] == 2 || rt[m] == 2) {
      const int lx = atomicAdd(&lcnt[r], 1);
      llist[r * 512 + lx] = m;
    }
  }
}

// ---------------- build U (bf16) = [hl_leaf|0 , hr_leaf|0 , hx] per node ----------------
__global__ __launch_bounds__(256)
void k_ubuild(const float* __restrict__ hs, const int* __restrict__ meta,
              unsigned short* __restrict__ U)
{
  const int id = blockIdx.x, b = blockIdx.y;
  const int tid = threadIdx.x;
  const int* own = meta;
  const int* lt = meta + 512;
  const int* li = meta + 1024;
  const int* rt = meta + 1536;
  const int* ri = meta + 2048;
  const int* nn = meta + 3072;
  const int m = b * 32 + id;
  unsigned short* u = U + (size_t)m * K3;
  if (id >= nn[b]) {
    for (int i = tid; i < K3; i += 256) u[i] = 0;
    return;
  }
  const float* hl = (lt[m] == 1) ? hs + (size_t)(b * 32 + li[m]) * 1024 : nullptr;
  const float* hr = (rt[m] == 1) ? hs + (size_t)(b * 32 + ri[m]) * 1024 : nullptr;
  const float* hx = hs + (size_t)(b * 32 + own[m]) * 1024;
  for (int i = tid; i < 1024; i += 256) {
    u[i] = hl ? f2bf(hl[i]) : 0;
    u[1024 + i] = hr ? f2bf(hr[i]) : 0;
    u[2048 + i] = f2bf(hx[i]);
  }
}

// ---------------- tail: ALL compose rounds, 1 launch, custom barriers ----------------
// grid 320 (block owns 16 Wc rows, staged to LDS ONCE), block 256 = 4 waves.
__global__ __launch_bounds__(256)
void k_tail(const unsigned short* __restrict__ WcB, const int* __restrict__ meta,
            const float* __restrict__ gB, const float* __restrict__ cs,
            float* __restrict__ nodec, unsigned short* __restrict__ nodehb,
            float* __restrict__ linkacc, float* __restrict__ out,
            int* __restrict__ bar)
{
  const int* lt = meta + 512;
  const int* li = meta + 1024;
  const int* rt = meta + 1536;
  const int* ri = meta + 2048;
  const int* dcnt = meta + 3088;
  const int* dlist = meta + 3152;
  const int* llist = meta + 19536;
  const int bid = blockIdx.x;
  const int tid = threadIdx.x;
  const int wave = tid >> 6, lane = tid & 63;
  const int l15 = lane & 15, quad = lane >> 4;
  const int g0 = bid * 16;
  __shared__ __align__(16) unsigned short Bs[16 * 2048];  // 64 KB, whole kernel
  const short8 z8 = {0, 0, 0, 0, 0, 0, 0, 0};

  {
    const int row = tid & 15;
    const int kqb = tid >> 4;
#pragma unroll
    for (int it = 0; it < 16; ++it) {
      const int kq = kqb + it * 16;
      *(uint4*)&Bs[kq * 128 + row * 8] =
          *(const uint4*)&WcB[(size_t)(g0 + row) * K3 + kq * 8];
    }
  }
  __syncthreads();

  auto gate_phase = [&](int r, bool uselink) {
    const int cnt = dcnt[r];
    for (int w = bid * 256 + tid; w < cnt * 256; w += 320 * 256) {
      const int m = w >> 8;
      const int hj = (w & 255) * 4;
      const int node = dlist[r * 512 + m];
      const int base = node & ~31;
      const int ltv = lt[node], rtv = rt[node];
      const float* clp = (ltv == 2) ? &nodec[(size_t)(base + li[node]) * 1024]
                       : (ltv == 1) ? &cs[(size_t)(base + li[node]) * 1024] : nullptr;
      const float* crp = (rtv == 2) ? &nodec[(size_t)(base + ri[node]) * 1024]
                       : (rtv == 1) ? &cs[(size_t)(base + ri[node]) * 1024] : nullptr;
      const float* g = &gB[(size_t)node * H5 + hj];
      const float* la = &linkacc[(size_t)node * H5 + hj];
      const float4 gi4  = *(const float4*)&g[0];
      const float4 gfl4 = *(const float4*)&g[1024];
      const float4 gfr4 = *(const float4*)&g[2048];
      const float4 gu4  = *(const float4*)&g[3072];
      const float4 go4  = *(const float4*)&g[4096];
      float4 li4 = make_float4(0.f, 0.f, 0.f, 0.f), lf4 = li4, lr4 = li4,
             lu4 = li4, lo4 = li4;
      if (uselink) {
        li4 = *(const float4*)&la[0];
        lf4 = *(const float4*)&la[1024];
        lr4 = *(const float4*)&la[2048];
        lu4 = *(const float4*)&la[3072];
        lo4 = *(const float4*)&la[4096];
      }
      const float gis[4] = {gi4.x + li4.x, gi4.y + li4.y, gi4.z + li4.z, gi4.w + li4.w};
      const float gfs[4] = {gfl4.x + lf4.x, gfl4.y + lf4.y, gfl4.z + lf4.z, gfl4.w + lf4.w};
      const float grs[4] = {gfr4.x + lr4.x, gfr4.y + lr4.y, gfr4.z + lr4.z, gfr4.w + lr4.w};
      const float gus[4] = {gu4.x + lu4.x, gu4.y + lu4.y, gu4.z + lu4.z, gu4.w + lu4.w};
      const float gos[4] = {go4.x + lo4.x, go4.y + lo4.y, go4.z + lo4.z, go4.w + lo4.w};
      const bool isroot = (node & 31) == 0;
      const int sb = node >> 5;
#pragma unroll
      for (int q = 0; q < 4; ++q) {
        const float cl = clp ? clp[hj + q] : 0.0f;
        const float cr = crp ? crp[hj + q] : 0.0f;
        const float c = sigf(gfs[q]) * cl + sigf(grs[q]) * cr + sigf(gis[q]) * tanhf(gus[q]);
        const float h = sigf(gos[q]) * tanhf(c);
        nodec[(size_t)node * 1024 + hj + q] = c;
        nodehb[(size_t)node * 1024 + hj + q] = f2bf(h);
        if (isroot) {
          out[sb * 1024 + hj + q] = h;
          out[16384 + sb * 1024 + hj + q] = c;
        }
      }
    }
  };

  // round 1: gate-only
  gate_phase(1, false);
  int bi = 32;
  gbar(&bar[bi++], 320);

  for (int r = 2; r <= 31; ++r) {
    const int cnt = dcnt[r];
    if (cnt == 0) break;
    // ---- link phase ----
    for (int ch = wave; ch * 16 < cnt; ch += 4) {
      const int m0 = ch * 16;
      const int m = m0 + l15;
      int ofs_l = -1, ofs_r = -1;
      if (m < cnt) {
        const int node = llist[r * 512 + m];
        const int base = node & ~31;
        if (lt[node] == 2) ofs_l = (base + li[node]) * 1024;
        if (rt[node] == 2) ofs_r = (base + ri[node]) * 1024;
      }
      floatx4 acc = (floatx4){0.f, 0.f, 0.f, 0.f};
      const int kq = quad * 8;
#pragma unroll 4
      for (int s = 0; s < 32; ++s) {
        const int k = s * 32 + kq;
        const short8 b8 = *(const short8*)&Bs[(k >> 3) * 128 + l15 * 8];
        const short8 a8 = (ofs_l >= 0) ? *(const short8*)&nodehb[(size_t)ofs_l + k] : z8;
        acc = __builtin_amdgcn_mfma_f32_16x16x32_bf16(a8, b8, acc, 0, 0, 0);
      }
#pragma unroll 4
      for (int s = 32; s < 64; ++s) {
        const int k = s * 32 + kq;
        const short8 b8 = *(const short8*)&Bs[(k >> 3) * 128 + l15 * 8];
        const short8 a8 = (ofs_r >= 0) ? *(const short8*)&nodehb[(size_t)ofs_r + k - 1024] : z8;
        acc = __builtin_amdgcn_mfma_f32_16x16x32_bf16(a8, b8, acc, 0, 0, 0);
      }
#pragma unroll
      for (int i = 0; i < 4; ++i) {
        const int mm = m0 + quad * 4 + i;
        if (mm < cnt) {
          const int nodei = llist[r * 512 + mm];
          linkacc[(size_t)nodei * H5 + g0 + l15] = acc[i];
        }
      }
    }
    gbar(&bar[bi++], 320);
    // ---- gate phase ----
    gate_phase(r, true);
    if (r == 31 || dcnt[r + 1] == 0) break;
    gbar(&bar[bi++], 320);
  }
}

extern "C" void kernel_launch(void* const* d_in, const int* in_sizes, int n_in,
                              void* d_out, int out_size, void* d_ws, size_t ws_size,
                              hipStream_t stream) {
  const float* emb = (const float*)d_in[0];
  const int* len = (const int*)d_in[1];
  const float* Wihf = (const float*)d_in[2];
  const float* Whhf = (const float*)d_in[3];
  const float* bf = (const float*)d_in[4];
  const float* Wihb = (const float*)d_in[5];
  const float* Whhb = (const float*)d_in[6];
  const float* bb = (const float*)d_in[7];
  const float* Wr1 = (const float*)d_in[8];
  const float* Wr2 = (const float*)d_in[9];
  const float* Wc = (const float*)d_in[10];
  const float* bc = (const float*)d_in[11];
  float* out = (float*)d_out;

  float* ws = (float*)d_ws;
  float* Xf = ws;                                         // 1048576 f
  float* Xb = Xf + 1048576;                               // 1048576 f
  float* hs = Xb + 1048576;                               // 524288 f
  float* cs = hs + 524288;                                // 524288 f
  float* E1 = cs + 524288;                                // 131072 f
  unsigned short* U = (unsigned short*)(E1 + 131072);     // 786432 f
  float* gB = (float*)U + 786432;                         // 2621440 f
  float* nodec = gB + 2621440;                            // 524288 f
  unsigned short* nodehb = (unsigned short*)(nodec + 524288);     // 262144 f
  float* cbuf = (float*)nodehb + 262144;                  // 32768 f
  unsigned short* hbB = (unsigned short*)(cbuf + 32768);  // 16384 f
  unsigned short* WcB = (unsigned short*)((float*)hbB + 16384);   // 7864320 f
  unsigned short* WihfB = WcB + 15728640;                 // 1048576 sh
  unsigned short* WihbB = WihfB + 1048576;
  unsigned short* WhhfB = WihbB + 1048576;
  unsigned short* WhhbB = WhhfB + 1048576;
  unsigned short* embB = WhhbB + 1048576;                 // 262144 sh
  int* meta = (int*)(embB + 262144);                      // ~36K ints
  int* ksplit = meta + 36096;                             // 16*1056 ints
  int* bar = meta + 52992;                                // 128 barrier counters
  float* linkacc = ws;  // aliases Xf+Xb+hs (dead after k_ubuild)

  // bf16 conversions (+ zeroes barrier counters for this call)
  k_conv6<<<dim3(1920, 6), 256, 0, stream>>>(
      Wc, WcB, 15728640, Wihf, WihfB, 1048576, Wihb, WihbB, 1048576,
      Whhf, WhhfB, 1048576, Whhb, WhhbB, 1048576, emb, embB, 262144, bar);
  // rank projection (f32)
  k_gemm<<<dim3(4, 8), 256, 0, stream>>>(emb, 512, Wr1, 513, E1, 256, 512);
  // input projections
  k_xproj<<<dim3(16, 4, 2), 256, 0, stream>>>(embB, WihfB, WihbB, Xf, Xb);
  // recurrent scan: ONE launch, custom spin barriers (cooperative for co-residency)
  {
    void* args[] = {(void*)&Xf, (void*)&Xb, (void*)&WhhfB, (void*)&WhhbB,
                    (void*)&bf, (void*)&bb, (void*)&len, (void*)&hbB,
                    (void*)&cbuf, (void*)&hs, (void*)&cs, (void*)&bar};
    hipLaunchCooperativeKernel((const void*)k_scan, dim3(64), dim3(256),
                               args, 0, stream);
  }
  // split table (+dcnt/lcnt zeroing) + DFS walk
  k_score<<<dim3(16, 31), 256, 0, stream>>>(E1, Wr1, Wr2, len, ksplit, meta);
  k_walk<<<16, 64, 0, stream>>>(ksplit, len, meta);
  // precomputable part of every compose
  k_ubuild<<<dim3(32, 16), 256, 0, stream>>>(hs, meta, U);
  k_mfma_gemm<<<320, 512, 0, stream>>>(U, WcB, bc, gB);
  // ALL compose rounds: ONE launch, custom spin barriers
  {
    void* args[] = {(void*)&WcB, (void*)&meta, (void*)&gB, (void*)&cs,
                    (void*)&nodec, (void*)&nodehb, (void*)&linkacc, (void*)&out,
                    (void*)&bar};
    hipLaunchCooperativeKernel((const void*)k_tail, dim3(320), dim3(256),
                               args, 0, stream);
  }
}